// Round 1
// baseline (196.363 us; speedup 1.0000x reference)
//
#include <hip/hip_runtime.h>

// out[pid] = verified_id[16*pid + accept_lens[pid] - 1], BS = 2,097,152.
//
// R2: delete the LDS round-trip. In the coalesced staging pattern
// (thread t loads float4 #(t + 256k)), the quarter-of-row covered is
// (t+256k)&3 == t&3 — CONSTANT across k — and the row is (t>>2)+64k.
// So each thread permanently owns quarter (t&3) of 4 rows. The pick
// "is the wanted element in my quarter?" is a local predicate:
//     idx = len-1;  hit iff (idx>>2) == (t&3)
// and exactly one of the 4 owning threads hits per row. The hitting
// thread cndmask-selects the component and stores directly.
//
// Coalescing:
//  - verified_id: lane i reads float4 #(base+i) -> perfect 1 KiB/wave instr.
//  - accept_lens: 4 consecutive lanes broadcast-read the same int; a wave
//    touches 16 consecutive ints = one 64 B line per instruction.
//  - out: the 16 active lanes of a wave store 16 consecutive floats =
//    exactly one full 64 B line per wave store.
// No LDS, no __syncthreads, no barrier vmcnt(0) drain — pure stream.

#define NUM_DRAFT 16

__global__ __launch_bounds__(256) void gather_verified_direct(
        const float* __restrict__ verified_id,
        const int*   __restrict__ accept_lens,
        float*       __restrict__ out) {
    const int t    = threadIdx.x;
    const int bpid = blockIdx.x * 256;   // first pid (row) of this block
    const int q    = t & 3;             // quarter of each row this thread owns
    const int r0   = t >> 2;            // base row-in-block

    const float4* src4 =
        reinterpret_cast<const float4*>(verified_id) + (size_t)bpid * 4;

#pragma unroll
    for (int k = 0; k < 4; ++k) {
        const int row  = r0 + 64 * k;           // row within block [0,256)
        const float4 f = src4[t + 256 * k];     // quarter q of row `row`
        const int idx  = accept_lens[bpid + row] - 1;   // 0..15, always valid
        if ((idx >> 2) == q) {
            // select component idx&3 via 2-level cndmask (no dynamic
            // vector indexing -> no scratch, rule #20)
            const float lo = (idx & 1) ? f.y : f.x;
            const float hi = (idx & 1) ? f.w : f.z;
            out[bpid + row] = (idx & 2) ? hi : lo;
        }
    }
}

extern "C" void kernel_launch(void* const* d_in, const int* in_sizes, int n_in,
                              void* d_out, int out_size, void* d_ws, size_t ws_size,
                              hipStream_t stream) {
    const float* verified_id = (const float*)d_in[0];
    const int*   accept_lens = (const int*)d_in[1];
    float*       out         = (float*)d_out;

    const int bs   = in_sizes[1];       // 2,097,152
    const int grid = bs / 256;          // 8192 blocks, 4 float4-rounds each

    gather_verified_direct<<<grid, 256, 0, stream>>>(verified_id, accept_lens, out);
}